// Round 9
// baseline (333.574 us; speedup 1.0000x reference)
//
#include <hip/hip_runtime.h>
#include <hip/hip_bf16.h>

// B,N,D,H = 4,2048,512,8 (DK=64). fp32 I/O; bf16 intermediates in ws.
// ws >= 43.0 MB PROVEN (R8 path-B wrote through byte 43.0M and passed).
// Layout: slab = NBD u16 (8.4 MB). [0]=Qp [1]=Kp [2]=Vpt [3..4]=Afp32(fp32)
// (slots 3,4 hold Qb,Kb before attn) [5 head]=Wb (0.5MB). Vb scratch = d_out.
#define B_  4
#define N_  2048
#define D_  512
#define H_  8

typedef unsigned short u16;
typedef __attribute__((ext_vector_type(8))) unsigned short ushort8;
typedef __attribute__((ext_vector_type(4))) unsigned short us4;
typedef __attribute__((ext_vector_type(8))) short short8;
typedef __attribute__((ext_vector_type(4))) short short4v;
typedef __attribute__((ext_vector_type(4))) float float4v;

__device__ __forceinline__ float bf2f(u16 u) {
    union { unsigned int i; float f; } v;
    v.i = ((unsigned int)u) << 16;
    return v.f;
}
__device__ __forceinline__ u16 f2bf(float f) {          // RNE
    union { float f; unsigned int i; } v;
    v.f = f;
    unsigned int r = v.i + 0x7FFFu + ((v.i >> 16) & 1u);
    return (u16)(r >> 16);
}
__device__ __forceinline__ u16 f2bf_fast(float f) {     // round-half-up
    union { float f; unsigned int i; } v;
    v.f = f;
    return (u16)((v.i + 0x8000u) >> 16);
}

// async global->LDS, 16B/lane, dest = wave-uniform base + lane*16 (m104 rule)
__device__ __forceinline__ void gload_lds16(const void* g, void* l) {
    __builtin_amdgcn_global_load_lds(
        (const __attribute__((address_space(1))) unsigned int*)g,
        (__attribute__((address_space(3))) unsigned int*)l, 16, 0, 0);
}

// ---------------------------------------------------------------------------
// wconv: Wq,Wo fp32 -> bf16, out = [Wqb | Wob]. grid (128, 2) x 256.
// ---------------------------------------------------------------------------
__global__ __launch_bounds__(256) void wconv(
    const float* __restrict__ Wq, const float* __restrict__ Wo,
    u16* __restrict__ out)
{
    const int idx = (blockIdx.x * 256 + threadIdx.x) * 8;
    const float* src = blockIdx.y ? Wo : Wq;
    u16* dst = out + (size_t)blockIdx.y * (D_ * D_) + idx;
    float4v a = *(const float4v*)(src + idx);
    float4v b = *(const float4v*)(src + idx + 4);
    ushort8 o;
    #pragma unroll
    for (int j = 0; j < 4; ++j) { o[j] = f2bf(a[j]); o[j + 4] = f2bf(b[j]); }
    *(ushort8*)dst = o;
}

// ---------------------------------------------------------------------------
// cvt3: Q,K,V fp32 -> bf16 into three separate dst slabs. grid (2048,3) x 256.
// ---------------------------------------------------------------------------
__global__ __launch_bounds__(256) void cvt3(
    const float* __restrict__ Q, const float* __restrict__ K,
    const float* __restrict__ V, u16* __restrict__ d0,
    u16* __restrict__ d1, u16* __restrict__ d2)
{
    const float* src = (blockIdx.y == 0) ? Q : ((blockIdx.y == 1) ? K : V);
    u16* dst = (blockIdx.y == 0) ? d0 : ((blockIdx.y == 1) ? d1 : d2);
    size_t idx = ((size_t)blockIdx.x * 256 + threadIdx.x) * 8;
    float4v a = *(const float4v*)(src + idx);
    float4v b = *(const float4v*)(src + idx + 4);
    ushort8 o;
    #pragma unroll
    for (int j = 0; j < 4; ++j) { o[j] = f2bf(a[j]); o[j + 4] = f2bf(b[j]); }
    *(ushort8*)(dst + idx) = o;
}

// ---------------------------------------------------------------------------
// MFMA GEMM: C[M,512] = X @ W^T + bias.  1D grid, XCD swizzle.
// INK: 0 = X fp32 (VALU cvt), 1 = X bf16 (global_load_lds).
// W always bf16 via gload. OUTB16: C bf16 (z==2 -> transposed Vpt[b][e][n]);
// else C fp32. 128x128 tile, 4 waves x 4x4 MFMA 16x16x32, BK=32.
// ---------------------------------------------------------------------------
template <int INK, bool OUTB16, int NZ>
__global__ __launch_bounds__(256) void proj_mfma(
    const void* __restrict__ X0v, const void* __restrict__ X1v,
    const void* __restrict__ X2v, const u16* __restrict__ Wb,
    const float* __restrict__ bias, void* __restrict__ C0v, int M)
{
    __shared__ u16 As[128][32];
    __shared__ u16 Bs[128][32];

    const int t = threadIdx.x;
    const int flat = blockIdx.x;
    const int xcd = flat & 7, rr = flat >> 3;
    const int eb = rr & 3, g = rr >> 2;
    const int zm = xcd + 8 * g;          // 0 .. 64*NZ-1
    const int z  = zm >> 6;
    const int e0 = eb * 128;
    const int m0 = (zm & 63) * 128;

    const void* Xv = (z == 0) ? X0v : ((z == 1) ? X1v : X2v);
    const int w = t >> 6, l = t & 63;
    const int lane16 = l & 15, quad = l >> 4;
    const int wr = (w >> 1) * 64;
    const int wc = (w & 1) * 64;

    float4v acc[4][4];
    #pragma unroll
    for (int i = 0; i < 4; ++i)
        #pragma unroll
        for (int j = 0; j < 4; ++j)
            acc[i][j] = (float4v){0.f, 0.f, 0.f, 0.f};

    for (int k0 = 0; k0 < 512; k0 += 32) {
        __syncthreads();

        // ---- stage A tile ----
        if (INK == 1) {
            const u16* X = (const u16*)Xv;
            #pragma unroll
            for (int i = 0; i < 2; ++i) {
                int r0 = w * 32 + i * 16;
                gload_lds16(X + (size_t)(m0 + r0 + (l >> 2)) * 512 + k0 + (l & 3) * 8,
                            &As[r0][0]);
            }
        } else {
            const float* X = (const float*)Xv;
            #pragma unroll
            for (int i = 0; i < 2; ++i) {
                int v   = t + 256 * i;
                int row = v >> 2;
                int c8  = (v & 3) * 8;
                const float* xp = X + (size_t)(m0 + row) * 512 + k0 + c8;
                float4v x0 = *(const float4v*)xp;
                float4v x1 = *(const float4v*)(xp + 4);
                ushort8 o;
                #pragma unroll
                for (int j = 0; j < 4; ++j) {
                    o[j]     = f2bf_fast(x0[j]);
                    o[j + 4] = f2bf_fast(x1[j]);
                }
                *(ushort8*)&As[row][c8] = o;
            }
        }
        // ---- stage B tile (W bf16 via gload) ----
        #pragma unroll
        for (int i = 0; i < 2; ++i) {
            int r0 = w * 32 + i * 16;
            gload_lds16(Wb + (size_t)(e0 + r0 + (l >> 2)) * 512 + k0 + (l & 3) * 8,
                        &Bs[r0][0]);
        }
        __syncthreads();

        short8 af[4], bfr[4];
        #pragma unroll
        for (int i = 0; i < 4; ++i)
            af[i] = *(const short8*)&As[wr + i * 16 + lane16][quad * 8];
        #pragma unroll
        for (int j = 0; j < 4; ++j)
            bfr[j] = *(const short8*)&Bs[wc + j * 16 + lane16][quad * 8];
        #pragma unroll
        for (int i = 0; i < 4; ++i)
            #pragma unroll
            for (int j = 0; j < 4; ++j)
                acc[i][j] = __builtin_amdgcn_mfma_f32_16x16x32_bf16(
                    af[i], bfr[j], acc[i][j], 0, 0, 0);
    }

    float bj[4];
    #pragma unroll
    for (int j = 0; j < 4; ++j) bj[j] = bias[e0 + wc + j * 16 + lane16];

    if (OUTB16) {
        if (z == 2) {   // transposed store: Vpt[b][e][n]
            u16* C = (u16*)C0v + 2 * (size_t)M * D_;
            #pragma unroll
            for (int i = 0; i < 4; ++i) {
                int mrow = m0 + wr + i * 16 + quad * 4;
                int bb = mrow >> 11, nb = mrow & (N_ - 1);
                #pragma unroll
                for (int j = 0; j < 4; ++j) {
                    int e = e0 + wc + j * 16 + lane16;
                    us4 o;
                    #pragma unroll
                    for (int r = 0; r < 4; ++r) o[r] = f2bf(acc[i][j][r] + bj[j]);
                    *(us4*)(C + (size_t)(bb * D_ + e) * N_ + nb) = o;
                }
            }
        } else {
            u16* C = (u16*)C0v + (size_t)z * (size_t)M * D_;
            #pragma unroll
            for (int i = 0; i < 4; ++i)
                #pragma unroll
                for (int j = 0; j < 4; ++j) {
                    int e = e0 + wc + j * 16 + lane16;
                    #pragma unroll
                    for (int r = 0; r < 4; ++r) {
                        int mrow = m0 + wr + i * 16 + quad * 4 + r;
                        C[(size_t)mrow * D_ + e] = f2bf(acc[i][j][r] + bj[j]);
                    }
                }
        }
    } else {
        float* C = (float*)C0v;
        #pragma unroll
        for (int i = 0; i < 4; ++i)
            #pragma unroll
            for (int j = 0; j < 4; ++j) {
                int e = e0 + wc + j * 16 + lane16;
                #pragma unroll
                for (int r = 0; r < 4; ++r) {
                    int mrow = m0 + wr + i * 16 + quad * 4 + r;
                    C[(size_t)mrow * D_ + e] = acc[i][j][r] + bj[j];
                }
            }
    }
}

// ---------------------------------------------------------------------------
// attn v4: heads-softmax fully register-local, NO P LDS round-trip.
// Identity: S^T = K.Q^T via mfma(A=kfrag, B=qfrag) gives C-layout
// (row=m=quad*4+r, col=n=lane16) == A-operand layout of mfma 16x16x16
// (A[n=lane&15][k=m=quad*4+j]). Softmax over h per lane, pack -> pfrag.
// PV: aacc[h][dt] += mfma_16x16x16(pfrag[h], vfrag) with V B-frags as
// contiguous ds_read_b64 from Vs[d][m]. 64 n-rows/block (4 waves x 16),
// m-chunks of 32 (Ks gload, Vs b128), 2 barriers/chunk. SPLIT=4 m-segments,
// results accumulated with fp32 atomicAdd into A (pre-zeroed).
// grid = 16 combos (b,z; XCD-pinned via flat&7) x 32 ntiles = 512 blocks.
// LDS 74,240 B -> 2 blocks/CU -> 8 waves/CU.
// ---------------------------------------------------------------------------
__global__ __launch_bounds__(256, 2) void attn_mfma4(
    const u16* __restrict__ Qp, const u16* __restrict__ Kp,
    const u16* __restrict__ Vpt, float* __restrict__ A)
{
    __shared__ u16 Ks[32][520];     // 33,280 B (K[m][d], pad: 2-way-free reads)
    __shared__ u16 Vs[512][40];     // 40,960 B (V^T[d][m], pad: ~2-way reads)

    const int t = threadIdx.x;
    const int w = t >> 6, l = t & 63;
    const int lane16 = l & 15, quad = l >> 4;

    const int flat  = blockIdx.x;
    const int combo = flat & 15;        // (b,z): xcd = combo&7 -> 2 combos/XCD
    const int ntile = flat >> 4;        // 0..31
    const int b = combo >> 2;
    const int z = combo & 3;
    const int n0 = ntile * 64 + w * 16; // wave-private 16 q-rows
    const int seg  = N_ / 4;            // 512
    const int mbeg = z * seg;

    // Q fragments: 8 heads x k=64 (A/B-layout identical), persistent
    short8 qfrag[8][2];
    {
        const u16* qb = Qp + ((size_t)(b * N_ + n0 + lane16) * D_ + quad * 8);
        #pragma unroll
        for (int h = 0; h < 8; ++h)
            #pragma unroll
            for (int dc = 0; dc < 2; ++dc)
                qfrag[h][dc] = *(const short8*)(qb + h * 64 + dc * 32);
    }

    float4v aacc[8][4];                 // 8 heads x 4 d-tiles
    #pragma unroll
    for (int h = 0; h < 8; ++h)
        #pragma unroll
        for (int dt = 0; dt < 4; ++dt)
            aacc[h][dt] = (float4v){0.f, 0.f, 0.f, 0.f};

    for (int mc = mbeg; mc < mbeg + seg; mc += 32) {
        __syncthreads();   // WAR: prev chunk's Ks/Vs reads complete

        // ---- stage K: 32 rows x 1KB via gload (row per instr, contiguous) ----
        #pragma unroll
        for (int i = 0; i < 8; ++i) {
            int row = w * 8 + i;
            gload_lds16(Kp + (size_t)(b * N_ + mc + row) * D_ + l * 8, &Ks[row][0]);
        }
        // ---- stage V^T: 512 d-rows x 32 m ----
        #pragma unroll
        for (int i = 0; i < 8; ++i) {
            int v = i * 256 + t;
            int d = v >> 2, part = v & 3;
            *(ushort8*)&Vs[d][part * 8] =
                *(const ushort8*)(Vpt + (size_t)(b * D_ + d) * N_ + mc + part * 8);
        }
        __syncthreads();   // staging visible

        #pragma unroll
        for (int msub = 0; msub < 2; ++msub) {
            // ---- S^T = K.Q^T for all 8 heads (16m x 16n), k=64 ----
            float4v sacc[8];
            #pragma unroll
            for (int h = 0; h < 8; ++h) sacc[h] = (float4v){0.f, 0.f, 0.f, 0.f};
            #pragma unroll
            for (int h = 0; h < 8; ++h)
                #pragma unroll
                for (int dc = 0; dc < 2; ++dc) {
                    short8 kf = *(const short8*)
                        &Ks[msub * 16 + lane16][h * 64 + dc * 32 + quad * 8];
                    sacc[h] = __builtin_amdgcn_mfma_f32_16x16x32_bf16(
                        kf, qfrag[h][dc], sacc[h], 0, 0, 0);   // A=K, B=Q^T
                }

            // ---- softmax over heads, per-lane; pack into PV A-frags ----
            short4v pfrag[8];
            #pragma unroll
            for (int r = 0; r < 4; ++r) {
                float e[8]; float sum = 0.f;
                #pragma unroll
                for (int h = 0; h < 8; ++h) {
                    e[h] = __expf(sacc[h][r] * 0.125f);   // 1/sqrt(64)
                    sum += e[h];
                }
                float inv = 1.f / sum;
                #pragma unroll
                for (int h = 0; h < 8; ++h)
                    pfrag[h][r] = (short)f2bf(e[h] * inv);
            }

            // ---- PV: k=16 (this msub), B-frag = ds_read_b64 of Vs[d][m] ----
            #pragma unroll
            for (int h = 0; h < 8; ++h)
                #pragma unroll
                for (int dt = 0; dt < 4; ++dt) {
                    short4v vf = *(const short4v*)
                        &Vs[h * 64 + dt * 16 + lane16][msub * 16 + quad * 4];
                    aacc[h][dt] = __builtin_amdgcn_mfma_f32_16x16x16bf16_1k(
                        pfrag[h], vf, aacc[h][dt], 0, 0, 0);
                }
        }
    }

    // ---- accumulate into A via fp32 atomics (coalesced over lane16=d) ----
    #pragma unroll
    for (int h = 0; h < 8; ++h)
        #pragma unroll
        for (int dt = 0; dt < 4; ++dt)
            #pragma unroll
            for (int r = 0; r < 4; ++r) {
                const int n = n0 + quad * 4 + r;
                const int d = h * 64 + dt * 16 + lane16;
                atomicAdd(&A[(size_t)(b * N_ + n) * D_ + d], aacc[h][dt][r]);
            }
}

// ---------------------------------------------------------------------------
extern "C" void kernel_launch(void* const* d_in, const int* in_sizes, int n_in,
                              void* d_out, int out_size, void* d_ws, size_t ws_size,
                              hipStream_t stream)
{
    const float* Q  = (const float*)d_in[0];
    const float* K  = (const float*)d_in[1];
    const float* V  = (const float*)d_in[2];
    const float* Wq = (const float*)d_in[3];
    const float* bq = (const float*)d_in[4];
    const float* Wo = (const float*)d_in[5];
    const float* bo = (const float*)d_in[6];
    float* out = (float*)d_out;
    u16*   ws  = (u16*)d_ws;

    const size_t NBD = (size_t)B_ * N_ * D_;   // 4,194,304
    const int M = B_ * N_;                     // 8192

    u16*   Qp    = ws;                 // slab 0
    u16*   Kp    = ws + NBD;           // slab 1
    u16*   Vpt   = ws + 2 * NBD;       // slab 2
    u16*   Qb    = ws + 3 * NBD;       // slab 3 (then Afp32 low half)
    u16*   Kb    = ws + 4 * NBD;       // slab 4 (then Afp32 high half)
    float* Afp32 = (float*)(ws + 3 * NBD);     // slabs 3-4 as fp32
    u16*   Wb    = ws + 5 * NBD;       // 0.5 MB; total need = 43.0 MB (proven)
    u16*   Vb    = (u16*)d_out;        // scratch until proj2 overwrites

    // 1) weights + inputs -> bf16
    wconv<<<dim3(128, 2), dim3(256), 0, stream>>>(Wq, Wo, Wb);
    cvt3<<<dim3(2048, 3), dim3(256), 0, stream>>>(Q, K, V, Qb, Kb, Vb);

    // 2) shared-weight projections (source bug: Wq/bq for Q, K, AND V)
    proj_mfma<1, true, 3><<<dim3(768), dim3(256), 0, stream>>>(
        Qb, Kb, Vb, Wb, bq, Qp, M);     // -> Qp, Kp, Vpt(transposed)

    // 3) zero the fp32 attention accumulator
    hipMemsetAsync(Afp32, 0, NBD * sizeof(float), stream);

    // 4) attention (heads-softmax), SPLIT=4 m-segments, atomic fp32 accumulate
    attn_mfma4<<<dim3(512), dim3(256), 0, stream>>>(Qp, Kp, Vpt, Afp32);

    // 5) output projection: fp32 A @ Wo^T + bo -> fp32 d_out
    proj_mfma<0, false, 1><<<dim3(256), dim3(256), 0, stream>>>(
        Afp32, Afp32, Afp32, Wb + (size_t)D_ * D_, bo, out, M);
}